// Round 2
// baseline (4749.164 us; speedup 1.0000x reference)
//
#include <hip/hip_runtime.h>

#define N_NODES 50000
#define N_EDGES 800000
#define DIM 128
#define N_GRAPHS 64
// LDS layout: stride 128 (2 x 64 x 128 floats = 64 KB exactly) with per-row XOR
// swizzle to kill column-read bank conflicts. swz multiple of 4 keeps float4
// stores contiguous/aligned. (Round-1 bug: stride 127 made rows OVERLAP.)
#define SWZ(row) ((((row) >> 3) & 7) << 2)

__global__ void deg_kernel(const int* __restrict__ dst, float* __restrict__ deg) {
    int e = blockIdx.x * blockDim.x + threadIdx.x;
    if (e < N_EDGES) unsafeAtomicAdd(&deg[dst[e]], 1.0f);
}

__global__ void inv_kernel(float* __restrict__ deg) {
    int i = blockIdx.x * blockDim.x + threadIdx.x;
    if (i < N_NODES) deg[i] = 1.0f / fmaxf(deg[i], 1.0f);
}

// One edge handled by 32 threads (4 floats each): float4 gather + 4 fp32 HW atomics.
__global__ void scatter_kernel(const float* __restrict__ X, const int* __restrict__ src,
                               const int* __restrict__ dst, float* __restrict__ agg) {
    long long t = (long long)blockIdx.x * blockDim.x + threadIdx.x;
    int e = (int)(t >> 5);
    if (e >= N_EDGES) return;
    int c = ((int)t & 31) << 2;
    int s = src[e], d = dst[e];
    const float4 v = *(const float4*)(X + (size_t)s * DIM + c);
    float* a = agg + (size_t)d * DIM + c;
    unsafeAtomicAdd(a + 0, v.x);
    unsafeAtomicAdd(a + 1, v.y);
    unsafeAtomicAdd(a + 2, v.z);
    unsafeAtomicAdd(a + 3, v.w);
}

// out[n][j] = act( (agg[n]*inv[n]) @ Wl^T + bl + X[n] @ Wr^T )
// Tile: 64 nodes x 64 outputs per block, 4x4 per thread, two K-passes (Wl/agg then Wr/X).
__global__ __launch_bounds__(256, 2) void layer_kernel(
    const float* __restrict__ agg, const float* __restrict__ inv,
    const float* __restrict__ X, const float* __restrict__ Wl,
    const float* __restrict__ Wr, const float* __restrict__ bl,
    float* __restrict__ out, int relu)
{
    __shared__ float sW[64 * DIM];
    __shared__ float sF[64 * DIM];
    const int tid = threadIdx.x;
    const int nt = blockIdx.x, jt = blockIdx.y;
    const int jg = tid & 15, ng = tid >> 4;
    const int j0 = jg * 4, n0 = ng * 4;
    float acc[4][4] = {};

    for (int pass = 0; pass < 2; ++pass) {
        const float* __restrict__ W = pass ? Wr : Wl;
        const float* __restrict__ F = pass ? X : agg;
        __syncthreads();  // protect previous pass's LDS reads
        #pragma unroll
        for (int it = 0; it < 8; ++it) {
            int idx = tid + it * 256;      // 0..2047 -> 64 rows x 32 float4
            int row = idx >> 5;
            int c4 = (idx & 31) << 2;
            int cs = c4 ^ SWZ(row);
            float4 wv = *(const float4*)(W + (size_t)(jt * 64 + row) * DIM + c4);
            *(float4*)(&sW[row * DIM + cs]) = wv;
            int gn = nt * 64 + row;
            float4 fv = make_float4(0.f, 0.f, 0.f, 0.f);
            if (gn < N_NODES) {
                fv = *(const float4*)(F + (size_t)gn * DIM + c4);
                if (pass == 0) {
                    float s = inv[gn];
                    fv.x *= s; fv.y *= s; fv.z *= s; fv.w *= s;
                }
            }
            *(float4*)(&sF[row * DIM + cs]) = fv;
        }
        __syncthreads();
        #pragma unroll 4
        for (int k = 0; k < DIM; ++k) {
            float wv[4], fv[4];
            #pragma unroll
            for (int r = 0; r < 4; ++r) wv[r] = sW[(j0 + r) * DIM + (k ^ SWZ(j0 + r))];
            #pragma unroll
            for (int r = 0; r < 4; ++r) fv[r] = sF[(n0 + r) * DIM + (k ^ SWZ(n0 + r))];
            #pragma unroll
            for (int a = 0; a < 4; ++a)
                #pragma unroll
                for (int b = 0; b < 4; ++b)
                    acc[a][b] = fmaf(fv[a], wv[b], acc[a][b]);
        }
    }

    const int gj = jt * 64 + j0;
    float bb[4];
    #pragma unroll
    for (int r = 0; r < 4; ++r) bb[r] = bl[gj + r];
    #pragma unroll
    for (int a = 0; a < 4; ++a) {
        int gn = nt * 64 + n0 + a;
        if (gn < N_NODES) {
            float4 o;
            o.x = acc[a][0] + bb[0];
            o.y = acc[a][1] + bb[1];
            o.z = acc[a][2] + bb[2];
            o.w = acc[a][3] + bb[3];
            if (relu) {
                o.x = fmaxf(o.x, 0.f); o.y = fmaxf(o.y, 0.f);
                o.z = fmaxf(o.z, 0.f); o.w = fmaxf(o.w, 0.f);
            }
            *(float4*)(out + (size_t)gn * DIM + gj) = o;
        }
    }
}

// batch is sorted: block g binary-searches its node range, 128 threads sum columns.
__global__ void pool_kernel(const float* __restrict__ H, const int* __restrict__ batch,
                            float* __restrict__ out) {
    int g = blockIdx.x;
    int j = threadIdx.x;
    int lo = 0, hi = N_NODES;
    while (lo < hi) { int m = (lo + hi) >> 1; if (batch[m] < g) lo = m + 1; else hi = m; }
    int start = lo;
    lo = start; hi = N_NODES;
    while (lo < hi) { int m = (lo + hi) >> 1; if (batch[m] < g + 1) lo = m + 1; else hi = m; }
    int end = lo;
    float s = 0.f;
    for (int n = start; n < end; ++n) s += H[(size_t)n * DIM + j];
    int cnt = end - start;
    out[g * DIM + j] = s / (float)(cnt > 0 ? cnt : 1);
}

extern "C" void kernel_launch(void* const* d_in, const int* in_sizes, int n_in,
                              void* d_out, int out_size, void* d_ws, size_t ws_size,
                              hipStream_t stream) {
    const float* x    = (const float*)d_in[0];
    const int*   ei   = (const int*)d_in[1];
    const int*   src  = ei;
    const int*   dst  = ei + N_EDGES;
    const int*   batch = (const int*)d_in[2];
    const float* Wl0 = (const float*)d_in[3];
    const float* bl0 = (const float*)d_in[4];
    const float* Wr0 = (const float*)d_in[5];
    const float* Wl1 = (const float*)d_in[6];
    const float* bl1 = (const float*)d_in[7];
    const float* Wr1 = (const float*)d_in[8];
    const float* Wl2 = (const float*)d_in[9];
    const float* bl2 = (const float*)d_in[10];
    const float* Wr2 = (const float*)d_in[11];
    float* out = (float*)d_out;

    float* inv = (float*)d_ws;            // 50000 floats (deg -> inv in place)
    float* agg = inv + 65536;             // 6.4M floats
    float* h1  = agg + 6400000;           // 6.4M floats
    float* h2  = h1 + 6400000;            // 6.4M floats

    const size_t aggBytes = (size_t)N_NODES * DIM * sizeof(float);

    hipMemsetAsync(inv, 0, N_NODES * sizeof(float), stream);
    deg_kernel<<<(N_EDGES + 255) / 256, 256, 0, stream>>>(dst, inv);
    inv_kernel<<<(N_NODES + 255) / 256, 256, 0, stream>>>(inv);

    dim3 lgrid((N_NODES + 63) / 64, 2);
    const int sblocks = (int)(((long long)N_EDGES * 32 + 255) / 256);

    // layer 0
    hipMemsetAsync(agg, 0, aggBytes, stream);
    scatter_kernel<<<sblocks, 256, 0, stream>>>(x, src, dst, agg);
    layer_kernel<<<lgrid, 256, 0, stream>>>(agg, inv, x, Wl0, Wr0, bl0, h1, 1);
    // layer 1
    hipMemsetAsync(agg, 0, aggBytes, stream);
    scatter_kernel<<<sblocks, 256, 0, stream>>>(h1, src, dst, agg);
    layer_kernel<<<lgrid, 256, 0, stream>>>(agg, inv, h1, Wl1, Wr1, bl1, h2, 1);
    // layer 2
    hipMemsetAsync(agg, 0, aggBytes, stream);
    scatter_kernel<<<sblocks, 256, 0, stream>>>(h2, src, dst, agg);
    layer_kernel<<<lgrid, 256, 0, stream>>>(agg, inv, h2, Wl2, Wr2, bl2, h1, 0);

    pool_kernel<<<N_GRAPHS, DIM, 0, stream>>>(h1, batch, out);
}

// Round 3
// 869.659 us; speedup vs baseline: 5.4609x; 5.4609x over previous
//
#include <hip/hip_runtime.h>

#define N_NODES 50000
#define N_EDGES 800000
#define DIM 128
#define N_GRAPHS 64
#define BUCKET_CAP 64   // degrees ~Poisson(16); max over 50k nodes ~45. Guarded anyway.
#define SWZ(row) ((((row) >> 3) & 7) << 2)

// Build fixed-capacity per-dst buckets of src indices. cnt[] doubles as cursor
// and final degree. 800k int atomics over 50k counters (avg 16/ctr) — cheap.
__global__ void fill_kernel(const int* __restrict__ src, const int* __restrict__ dst,
                            int* __restrict__ cnt, int* __restrict__ bucket) {
    int e = blockIdx.x * blockDim.x + threadIdx.x;
    if (e >= N_EDGES) return;
    int d = dst[e];
    int pos = atomicAdd(&cnt[d], 1);
    if (pos < BUCKET_CAP) bucket[d * BUCKET_CAP + pos] = src[e];
}

// Pull-aggregation: one wave per node. Lane l owns columns [2l, 2l+1].
// Coalesced 512B row reads from X (25.6 MB table -> L2/L3 resident).
// Mean folded in: agg = sum * 1/max(deg,1).
__global__ __launch_bounds__(256) void gather_kernel(
    const float* __restrict__ X, const int* __restrict__ cnt,
    const int* __restrict__ bucket, float* __restrict__ agg) {
    int wave = (blockIdx.x * blockDim.x + threadIdx.x) >> 6;
    int lane = threadIdx.x & 63;
    if (wave >= N_NODES) return;
    int n = wave;
    int c = cnt[n];
    const int* b = bucket + (size_t)n * BUCKET_CAP;
    float2 acc = make_float2(0.f, 0.f);
    int k = 0;
    for (; k + 1 < c; k += 2) {
        int s0 = b[k], s1 = b[k + 1];
        float2 v0 = *(const float2*)(X + (size_t)s0 * DIM + lane * 2);
        float2 v1 = *(const float2*)(X + (size_t)s1 * DIM + lane * 2);
        acc.x += v0.x + v1.x;
        acc.y += v0.y + v1.y;
    }
    if (k < c) {
        int s0 = b[k];
        float2 v0 = *(const float2*)(X + (size_t)s0 * DIM + lane * 2);
        acc.x += v0.x;
        acc.y += v0.y;
    }
    float inv = 1.0f / (float)(c > 0 ? c : 1);
    acc.x *= inv; acc.y *= inv;
    *(float2*)(agg + (size_t)n * DIM + lane * 2) = acc;
}

// out[n][j] = act( agg[n] @ Wl^T + bl + X[n] @ Wr^T )   (agg already mean-scaled)
// Tile: 64 nodes x 64 outputs per block, 4x4 per thread, two K-passes.
__global__ __launch_bounds__(256, 2) void layer_kernel(
    const float* __restrict__ agg, const float* __restrict__ X,
    const float* __restrict__ Wl, const float* __restrict__ Wr,
    const float* __restrict__ bl, float* __restrict__ out, int relu)
{
    __shared__ float sW[64 * DIM];
    __shared__ float sF[64 * DIM];
    const int tid = threadIdx.x;
    const int nt = blockIdx.x, jt = blockIdx.y;
    const int jg = tid & 15, ng = tid >> 4;
    const int j0 = jg * 4, n0 = ng * 4;
    float acc[4][4] = {};

    for (int pass = 0; pass < 2; ++pass) {
        const float* __restrict__ W = pass ? Wr : Wl;
        const float* __restrict__ F = pass ? X : agg;
        __syncthreads();
        #pragma unroll
        for (int it = 0; it < 8; ++it) {
            int idx = tid + it * 256;
            int row = idx >> 5;
            int c4 = (idx & 31) << 2;
            int cs = c4 ^ SWZ(row);
            float4 wv = *(const float4*)(W + (size_t)(jt * 64 + row) * DIM + c4);
            *(float4*)(&sW[row * DIM + cs]) = wv;
            int gn = nt * 64 + row;
            float4 fv = make_float4(0.f, 0.f, 0.f, 0.f);
            if (gn < N_NODES) fv = *(const float4*)(F + (size_t)gn * DIM + c4);
            *(float4*)(&sF[row * DIM + cs]) = fv;
        }
        __syncthreads();
        #pragma unroll 4
        for (int k = 0; k < DIM; ++k) {
            float wv[4], fv[4];
            #pragma unroll
            for (int r = 0; r < 4; ++r) wv[r] = sW[(j0 + r) * DIM + (k ^ SWZ(j0 + r))];
            #pragma unroll
            for (int r = 0; r < 4; ++r) fv[r] = sF[(n0 + r) * DIM + (k ^ SWZ(n0 + r))];
            #pragma unroll
            for (int a = 0; a < 4; ++a)
                #pragma unroll
                for (int b = 0; b < 4; ++b)
                    acc[a][b] = fmaf(fv[a], wv[b], acc[a][b]);
        }
    }

    const int gj = jt * 64 + j0;
    float bb[4];
    #pragma unroll
    for (int r = 0; r < 4; ++r) bb[r] = bl[gj + r];
    #pragma unroll
    for (int a = 0; a < 4; ++a) {
        int gn = nt * 64 + n0 + a;
        if (gn < N_NODES) {
            float4 o;
            o.x = acc[a][0] + bb[0];
            o.y = acc[a][1] + bb[1];
            o.z = acc[a][2] + bb[2];
            o.w = acc[a][3] + bb[3];
            if (relu) {
                o.x = fmaxf(o.x, 0.f); o.y = fmaxf(o.y, 0.f);
                o.z = fmaxf(o.z, 0.f); o.w = fmaxf(o.w, 0.f);
            }
            *(float4*)(out + (size_t)gn * DIM + gj) = o;
        }
    }
}

// batch is sorted: block g binary-searches its node range, 128 threads sum columns.
__global__ void pool_kernel(const float* __restrict__ H, const int* __restrict__ batch,
                            float* __restrict__ out) {
    int g = blockIdx.x;
    int j = threadIdx.x;
    int lo = 0, hi = N_NODES;
    while (lo < hi) { int m = (lo + hi) >> 1; if (batch[m] < g) lo = m + 1; else hi = m; }
    int start = lo;
    lo = start; hi = N_NODES;
    while (lo < hi) { int m = (lo + hi) >> 1; if (batch[m] < g + 1) lo = m + 1; else hi = m; }
    int end = lo;
    float s = 0.f;
    for (int n = start; n < end; ++n) s += H[(size_t)n * DIM + j];
    int cnt = end - start;
    out[g * DIM + j] = s / (float)(cnt > 0 ? cnt : 1);
}

extern "C" void kernel_launch(void* const* d_in, const int* in_sizes, int n_in,
                              void* d_out, int out_size, void* d_ws, size_t ws_size,
                              hipStream_t stream) {
    const float* x    = (const float*)d_in[0];
    const int*   ei   = (const int*)d_in[1];
    const int*   src  = ei;
    const int*   dst  = ei + N_EDGES;
    const int*   batch = (const int*)d_in[2];
    const float* Wl0 = (const float*)d_in[3];
    const float* bl0 = (const float*)d_in[4];
    const float* Wr0 = (const float*)d_in[5];
    const float* Wl1 = (const float*)d_in[6];
    const float* bl1 = (const float*)d_in[7];
    const float* Wr1 = (const float*)d_in[8];
    const float* Wl2 = (const float*)d_in[9];
    const float* bl2 = (const float*)d_in[10];
    const float* Wr2 = (const float*)d_in[11];
    float* out = (float*)d_out;

    int*   cnt    = (int*)d_ws;                       // 65536 ints
    int*   bucket = cnt + 65536;                      // 50000*64 ints = 3.2M
    float* agg    = (float*)(bucket + N_NODES * BUCKET_CAP);
    float* h1     = agg + 6400000;
    float* h2     = h1 + 6400000;

    hipMemsetAsync(cnt, 0, N_NODES * sizeof(int), stream);
    fill_kernel<<<(N_EDGES + 255) / 256, 256, 0, stream>>>(src, dst, cnt, bucket);

    dim3 lgrid((N_NODES + 63) / 64, 2);
    const int ggrid = (N_NODES * 64 + 255) / 256;   // one wave per node

    // layer 0
    gather_kernel<<<ggrid, 256, 0, stream>>>(x, cnt, bucket, agg);
    layer_kernel<<<lgrid, 256, 0, stream>>>(agg, x, Wl0, Wr0, bl0, h1, 1);
    // layer 1
    gather_kernel<<<ggrid, 256, 0, stream>>>(h1, cnt, bucket, agg);
    layer_kernel<<<lgrid, 256, 0, stream>>>(agg, h1, Wl1, Wr1, bl1, h2, 1);
    // layer 2
    gather_kernel<<<ggrid, 256, 0, stream>>>(h2, cnt, bucket, agg);
    layer_kernel<<<lgrid, 256, 0, stream>>>(agg, h2, Wl2, Wr2, bl2, h1, 0);

    pool_kernel<<<N_GRAPHS, DIM, 0, stream>>>(h1, batch, out);
}

// Round 4
// 704.983 us; speedup vs baseline: 6.7366x; 1.2336x over previous
//
#include <hip/hip_runtime.h>

#define N_NODES 50000
#define N_EDGES 800000
#define DIM 128
#define N_GRAPHS 64
#define BUCKET_CAP 64   // degrees ~Poisson(16); max over 50k nodes ~45. Guarded anyway.
#define P_BLOCKS 512    // pool stage-1 parallelism
#define SWZ(row) ((((row) >> 3) & 7) << 2)

// Build fixed-capacity per-dst buckets of src indices. cnt[] doubles as cursor
// and final degree. 800k int atomics over 50k counters (avg 16/ctr) — cheap.
__global__ void fill_kernel(const int* __restrict__ src, const int* __restrict__ dst,
                            int* __restrict__ cnt, int* __restrict__ bucket) {
    int e = blockIdx.x * blockDim.x + threadIdx.x;
    if (e >= N_EDGES) return;
    int d = dst[e];
    int pos = atomicAdd(&cnt[d], 1);
    if (pos < BUCKET_CAP) bucket[d * BUCKET_CAP + pos] = src[e];
}

// Pull-aggregation: one wave per node. Lane l owns columns [2l, 2l+1].
__global__ __launch_bounds__(256) void gather_kernel(
    const float* __restrict__ X, const int* __restrict__ cnt,
    const int* __restrict__ bucket, float* __restrict__ agg) {
    int wave = (blockIdx.x * blockDim.x + threadIdx.x) >> 6;
    int lane = threadIdx.x & 63;
    if (wave >= N_NODES) return;
    int n = wave;
    int c = cnt[n];
    const int* b = bucket + (size_t)n * BUCKET_CAP;
    float2 acc = make_float2(0.f, 0.f);
    int k = 0;
    for (; k + 1 < c; k += 2) {
        int s0 = b[k], s1 = b[k + 1];
        float2 v0 = *(const float2*)(X + (size_t)s0 * DIM + lane * 2);
        float2 v1 = *(const float2*)(X + (size_t)s1 * DIM + lane * 2);
        acc.x += v0.x + v1.x;
        acc.y += v0.y + v1.y;
    }
    if (k < c) {
        int s0 = b[k];
        float2 v0 = *(const float2*)(X + (size_t)s0 * DIM + lane * 2);
        acc.x += v0.x;
        acc.y += v0.y;
    }
    float inv = 1.0f / (float)(c > 0 ? c : 1);
    acc.x *= inv; acc.y *= inv;
    *(float2*)(agg + (size_t)n * DIM + lane * 2) = acc;
}

// out[n][j] = act( agg[n] @ Wl^T + bl + X[n] @ Wr^T )   (agg already mean-scaled)
__global__ __launch_bounds__(256, 2) void layer_kernel(
    const float* __restrict__ agg, const float* __restrict__ X,
    const float* __restrict__ Wl, const float* __restrict__ Wr,
    const float* __restrict__ bl, float* __restrict__ out, int relu)
{
    __shared__ float sW[64 * DIM];
    __shared__ float sF[64 * DIM];
    const int tid = threadIdx.x;
    const int nt = blockIdx.x, jt = blockIdx.y;
    const int jg = tid & 15, ng = tid >> 4;
    const int j0 = jg * 4, n0 = ng * 4;
    float acc[4][4] = {};

    for (int pass = 0; pass < 2; ++pass) {
        const float* __restrict__ W = pass ? Wr : Wl;
        const float* __restrict__ F = pass ? X : agg;
        __syncthreads();
        #pragma unroll
        for (int it = 0; it < 8; ++it) {
            int idx = tid + it * 256;
            int row = idx >> 5;
            int c4 = (idx & 31) << 2;
            int cs = c4 ^ SWZ(row);
            float4 wv = *(const float4*)(W + (size_t)(jt * 64 + row) * DIM + c4);
            *(float4*)(&sW[row * DIM + cs]) = wv;
            int gn = nt * 64 + row;
            float4 fv = make_float4(0.f, 0.f, 0.f, 0.f);
            if (gn < N_NODES) fv = *(const float4*)(F + (size_t)gn * DIM + c4);
            *(float4*)(&sF[row * DIM + cs]) = fv;
        }
        __syncthreads();
        #pragma unroll 4
        for (int k = 0; k < DIM; ++k) {
            float wv[4], fv[4];
            #pragma unroll
            for (int r = 0; r < 4; ++r) wv[r] = sW[(j0 + r) * DIM + (k ^ SWZ(j0 + r))];
            #pragma unroll
            for (int r = 0; r < 4; ++r) fv[r] = sF[(n0 + r) * DIM + (k ^ SWZ(n0 + r))];
            #pragma unroll
            for (int a = 0; a < 4; ++a)
                #pragma unroll
                for (int b = 0; b < 4; ++b)
                    acc[a][b] = fmaf(fv[a], wv[b], acc[a][b]);
        }
    }

    const int gj = jt * 64 + j0;
    float bb[4];
    #pragma unroll
    for (int r = 0; r < 4; ++r) bb[r] = bl[gj + r];
    #pragma unroll
    for (int a = 0; a < 4; ++a) {
        int gn = nt * 64 + n0 + a;
        if (gn < N_NODES) {
            float4 o;
            o.x = acc[a][0] + bb[0];
            o.y = acc[a][1] + bb[1];
            o.z = acc[a][2] + bb[2];
            o.w = acc[a][3] + bb[3];
            if (relu) {
                o.x = fmaxf(o.x, 0.f); o.y = fmaxf(o.y, 0.f);
                o.z = fmaxf(o.z, 0.f); o.w = fmaxf(o.w, 0.f);
            }
            *(float4*)(out + (size_t)gn * DIM + gj) = o;
        }
    }
}

// Pool stage 1: 512 blocks x 128 threads; block owns ~98 contiguous nodes.
// batch sorted -> block slice spans few graphs; flush register runs via atomics.
__global__ void pool1_kernel(const float* __restrict__ H, const int* __restrict__ batch,
                             float* __restrict__ pool) {
    const int per = (N_NODES + P_BLOCKS - 1) / P_BLOCKS;
    int n0 = blockIdx.x * per;
    int n1 = n0 + per; if (n1 > N_NODES) n1 = N_NODES;
    if (n0 >= n1) return;
    int j = threadIdx.x;
    float acc = 0.f;
    int g = batch[n0];
    for (int n = n0; n < n1; ++n) {
        int bg = batch[n];
        if (bg != g) {
            unsafeAtomicAdd(&pool[g * DIM + j], acc);
            acc = 0.f; g = bg;
        }
        acc += H[(size_t)n * DIM + j];
    }
    unsafeAtomicAdd(&pool[g * DIM + j], acc);
}

// Pool stage 2: divide by per-graph node count (binary search on sorted batch).
__global__ void pool2_kernel(const float* __restrict__ pool, const int* __restrict__ batch,
                             float* __restrict__ out) {
    int g = blockIdx.x;
    int j = threadIdx.x;
    int lo = 0, hi = N_NODES;
    while (lo < hi) { int m = (lo + hi) >> 1; if (batch[m] < g) lo = m + 1; else hi = m; }
    int start = lo;
    lo = start; hi = N_NODES;
    while (lo < hi) { int m = (lo + hi) >> 1; if (batch[m] < g + 1) lo = m + 1; else hi = m; }
    int cnt = lo - start;
    out[g * DIM + j] = pool[g * DIM + j] / (float)(cnt > 0 ? cnt : 1);
}

extern "C" void kernel_launch(void* const* d_in, const int* in_sizes, int n_in,
                              void* d_out, int out_size, void* d_ws, size_t ws_size,
                              hipStream_t stream) {
    const float* x    = (const float*)d_in[0];
    const int*   ei   = (const int*)d_in[1];
    const int*   src  = ei;
    const int*   dst  = ei + N_EDGES;
    const int*   batch = (const int*)d_in[2];
    const float* Wl0 = (const float*)d_in[3];
    const float* bl0 = (const float*)d_in[4];
    const float* Wr0 = (const float*)d_in[5];
    const float* Wl1 = (const float*)d_in[6];
    const float* bl1 = (const float*)d_in[7];
    const float* Wr1 = (const float*)d_in[8];
    const float* Wl2 = (const float*)d_in[9];
    const float* bl2 = (const float*)d_in[10];
    const float* Wr2 = (const float*)d_in[11];
    float* out = (float*)d_out;

    int*   cnt    = (int*)d_ws;                       // 65536 ints
    int*   bucket = cnt + 65536;                      // 50000*64 ints = 3.2M
    float* agg    = (float*)(bucket + N_NODES * BUCKET_CAP);
    float* h1     = agg + 6400000;
    float* h2     = h1 + 6400000;
    float* pool   = h2 + 6400000;                     // 64*128 floats

    hipMemsetAsync(cnt, 0, N_NODES * sizeof(int), stream);
    hipMemsetAsync(pool, 0, N_GRAPHS * DIM * sizeof(float), stream);
    fill_kernel<<<(N_EDGES + 255) / 256, 256, 0, stream>>>(src, dst, cnt, bucket);

    dim3 lgrid((N_NODES + 63) / 64, 2);
    const int ggrid = (N_NODES * 64 + 255) / 256;   // one wave per node

    // layer 0
    gather_kernel<<<ggrid, 256, 0, stream>>>(x, cnt, bucket, agg);
    layer_kernel<<<lgrid, 256, 0, stream>>>(agg, x, Wl0, Wr0, bl0, h1, 1);
    // layer 1
    gather_kernel<<<ggrid, 256, 0, stream>>>(h1, cnt, bucket, agg);
    layer_kernel<<<lgrid, 256, 0, stream>>>(agg, h1, Wl1, Wr1, bl1, h2, 1);
    // layer 2
    gather_kernel<<<ggrid, 256, 0, stream>>>(h2, cnt, bucket, agg);
    layer_kernel<<<lgrid, 256, 0, stream>>>(agg, h2, Wl2, Wr2, bl2, h1, 0);

    pool1_kernel<<<P_BLOCKS, DIM, 0, stream>>>(h1, batch, pool);
    pool2_kernel<<<N_GRAPHS, DIM, 0, stream>>>(pool, batch, out);
}

// Round 5
// 364.438 us; speedup vs baseline: 13.0315x; 1.9344x over previous
//
#include <hip/hip_runtime.h>

#define N_NODES 50000
#define N_EDGES 800000
#define DIM 128
#define KTOT 256        // [agg | x] concatenated along k
#define N_GRAPHS 64
#define BUCKET_CAP 64
#define P_BLOCKS 512
#define LSTR 264        // LDS A-tile row stride in bf16 (+8 pad -> conflict-free b128)

typedef __attribute__((ext_vector_type(8))) short bf16x8;
typedef __attribute__((ext_vector_type(16))) float f32x16;

__device__ __forceinline__ float bf2f(unsigned short u) {
    unsigned int v = ((unsigned int)u) << 16;
    return __uint_as_float(v);
}
__device__ __forceinline__ unsigned short f2bf(float f) {
    unsigned int v = __float_as_uint(f);
    unsigned int r = (v + 0x7fffu + ((v >> 16) & 1u)) >> 16;   // RNE
    return (unsigned short)r;
}

// ---------- setup: buckets + casts ----------
__global__ void fill_kernel(const int* __restrict__ src, const int* __restrict__ dst,
                            int* __restrict__ cnt, int* __restrict__ bucket) {
    int e = blockIdx.x * blockDim.x + threadIdx.x;
    if (e >= N_EDGES) return;
    int d = dst[e];
    int pos = atomicAdd(&cnt[d], 1);
    if (pos < BUCKET_CAP) bucket[d * BUCKET_CAP + pos] = src[e];
}

__global__ void castx_kernel(const float* __restrict__ x, ushort* __restrict__ xb) {
    int i = blockIdx.x * blockDim.x + threadIdx.x;   // float4 index
    if (i >= N_NODES * DIM / 4) return;
    float4 v = ((const float4*)x)[i];
    ushort4 o;
    o.x = f2bf(v.x); o.y = f2bf(v.y); o.z = f2bf(v.z); o.w = f2bf(v.w);
    ((ushort4*)xb)[i] = o;
}

// wb layout per layer: [128 j][256 k] with k<128 = Wl, k>=128 = Wr
__global__ void castw_kernel(const float* __restrict__ Wl0, const float* __restrict__ Wr0,
                             const float* __restrict__ Wl1, const float* __restrict__ Wr1,
                             const float* __restrict__ Wl2, const float* __restrict__ Wr2,
                             ushort* __restrict__ wb) {
    int id = blockIdx.x * blockDim.x + threadIdx.x;   // 3*128*256 = 98304
    if (id >= 3 * DIM * KTOT) return;
    int l = id >> 15;          // /32768
    int r = id & 32767;
    int j = r >> 8, k = r & 255;
    const float* Wl = (l == 0) ? Wl0 : (l == 1) ? Wl1 : Wl2;
    const float* Wr = (l == 0) ? Wr0 : (l == 1) ? Wr1 : Wr2;
    float v = (k < DIM) ? Wl[j * DIM + k] : Wr[j * DIM + k - DIM];
    wb[id] = f2bf(v);
}

// ---------- pull aggregation (bf16 in/out, fp32 accum) ----------
// One wave per node; lane owns cols [2l, 2l+1] (one uint = 2 bf16). 4-edge unroll.
__global__ __launch_bounds__(256) void gather_kernel(
    const ushort* __restrict__ X, const int* __restrict__ cnt,
    const int* __restrict__ bucket, ushort* __restrict__ agg) {
    int n = (blockIdx.x * blockDim.x + threadIdx.x) >> 6;
    int lane = threadIdx.x & 63;
    if (n >= N_NODES) return;
    int c = cnt[n];
    int cl = c < BUCKET_CAP ? c : BUCKET_CAP;
    const int* b = bucket + (size_t)n * BUCKET_CAP;
    float ax = 0.f, ay = 0.f;
    int k = 0;
    for (; k + 3 < cl; k += 4) {
        int s0 = b[k], s1 = b[k+1], s2 = b[k+2], s3 = b[k+3];
        unsigned int u0 = *(const unsigned int*)(X + (size_t)s0 * DIM + lane * 2);
        unsigned int u1 = *(const unsigned int*)(X + (size_t)s1 * DIM + lane * 2);
        unsigned int u2 = *(const unsigned int*)(X + (size_t)s2 * DIM + lane * 2);
        unsigned int u3 = *(const unsigned int*)(X + (size_t)s3 * DIM + lane * 2);
        ax += bf2f(u0 & 0xffff) + bf2f(u1 & 0xffff) + bf2f(u2 & 0xffff) + bf2f(u3 & 0xffff);
        ay += bf2f(u0 >> 16)    + bf2f(u1 >> 16)    + bf2f(u2 >> 16)    + bf2f(u3 >> 16);
    }
    for (; k < cl; ++k) {
        unsigned int u0 = *(const unsigned int*)(X + (size_t)b[k] * DIM + lane * 2);
        ax += bf2f(u0 & 0xffff);
        ay += bf2f(u0 >> 16);
    }
    float inv = 1.0f / (float)(c > 0 ? c : 1);
    unsigned int o = ((unsigned int)f2bf(ay * inv) << 16) | f2bf(ax * inv);
    *(unsigned int*)(agg + (size_t)n * DIM + lane * 2) = o;
}

// ---------- MFMA layer: out[50000x128] = [agg|h][50000x256] . W[128x256]^T ----------
// 512 thr = 8 waves. Block tile: 64 nodes x 128 j. Wave: mh=w&1 (32 nodes), jq=w>>1 (32 j).
// W fragments in VGPRs (loaded once from L2); LDS stages A-tile only.
__global__ __launch_bounds__(512, 4) void layer_mfma(
    const ushort* __restrict__ aggb, const ushort* __restrict__ hb,
    const ushort* __restrict__ wb, const float* __restrict__ bl,
    ushort* __restrict__ outb, int relu)
{
    __shared__ ushort sA[64 * LSTR];
    const int tid = threadIdx.x;
    const int lane = tid & 63, w = tid >> 6;
    const int mh = w & 1, jq = w >> 1;
    const int n0 = blockIdx.x * 64;

    // W fragments: lane l holds W[jq*32 + (l&31)][kt*16 + (l>>5)*8 .. +7]  (B = W^T)
    bf16x8 bw[16];
    {
        const ushort* wp = wb + (size_t)(jq * 32 + (lane & 31)) * KTOT + (lane >> 5) * 8;
        #pragma unroll
        for (int kt = 0; kt < 16; ++kt)
            bw[kt] = *(const bf16x8*)(wp + kt * 16);
    }

    // Stage A tile: 64 rows x 256 bf16 (k<128 from aggb, else hb). 2048 b128 chunks.
    #pragma unroll
    for (int it = 0; it < 4; ++it) {
        int c = tid + it * 512;
        int row = c >> 5;              // 32 chunks/row
        int k8 = (c & 31) * 8;
        int gn = n0 + row;
        bf16x8 v = (bf16x8){0,0,0,0,0,0,0,0};
        if (gn < N_NODES) {
            const ushort* p = (k8 < DIM) ? (aggb + (size_t)gn * DIM + k8)
                                         : (hb + (size_t)gn * DIM + (k8 - DIM));
            v = *(const bf16x8*)p;
        }
        *(bf16x8*)(&sA[row * LSTR + k8]) = v;
    }
    __syncthreads();

    // K-loop: 16 steps of 32x32x16 MFMA
    f32x16 acc = {};
    const int arow = mh * 32 + (lane & 31);
    const int akoff = (lane >> 5) * 8;
    #pragma unroll
    for (int kt = 0; kt < 16; ++kt) {
        bf16x8 a = *(const bf16x8*)(&sA[arow * LSTR + kt * 16 + akoff]);
        acc = __builtin_amdgcn_mfma_f32_32x32x16_bf16(a, bw[kt], acc, 0, 0, 0);
    }

    // Epilogue: C/D map col=lane&31, row=(reg&3)+8*(reg>>2)+4*(lane>>5)  [m74/m101]
    const int col = lane & 31;
    const int j = jq * 32 + col;
    const float bias = bl[j];
    #pragma unroll
    for (int r = 0; r < 16; ++r) {
        int row = (r & 3) + 8 * (r >> 2) + 4 * (lane >> 5);
        int gn = n0 + mh * 32 + row;
        if (gn < N_NODES) {
            float v = acc[r] + bias;
            if (relu) v = fmaxf(v, 0.f);
            outb[(size_t)gn * DIM + j] = f2bf(v);
        }
    }
}

// ---------- pool ----------
__global__ void pool1_kernel(const ushort* __restrict__ H, const int* __restrict__ batch,
                             float* __restrict__ pool) {
    const int per = (N_NODES + P_BLOCKS - 1) / P_BLOCKS;
    int n0 = blockIdx.x * per;
    int n1 = n0 + per; if (n1 > N_NODES) n1 = N_NODES;
    if (n0 >= n1) return;
    int j = threadIdx.x;
    float acc = 0.f;
    int g = batch[n0];
    for (int n = n0; n < n1; ++n) {
        int bg = batch[n];
        if (bg != g) {
            unsafeAtomicAdd(&pool[g * DIM + j], acc);
            acc = 0.f; g = bg;
        }
        acc += bf2f(H[(size_t)n * DIM + j]);
    }
    unsafeAtomicAdd(&pool[g * DIM + j], acc);
}

__global__ void pool2_kernel(const float* __restrict__ pool, const int* __restrict__ batch,
                             float* __restrict__ out) {
    int g = blockIdx.x;
    int j = threadIdx.x;
    int lo = 0, hi = N_NODES;
    while (lo < hi) { int m = (lo + hi) >> 1; if (batch[m] < g) lo = m + 1; else hi = m; }
    int start = lo;
    lo = start; hi = N_NODES;
    while (lo < hi) { int m = (lo + hi) >> 1; if (batch[m] < g + 1) lo = m + 1; else hi = m; }
    int cnt = lo - start;
    out[g * DIM + j] = pool[g * DIM + j] / (float)(cnt > 0 ? cnt : 1);
}

extern "C" void kernel_launch(void* const* d_in, const int* in_sizes, int n_in,
                              void* d_out, int out_size, void* d_ws, size_t ws_size,
                              hipStream_t stream) {
    const float* x    = (const float*)d_in[0];
    const int*   ei   = (const int*)d_in[1];
    const int*   src  = ei;
    const int*   dst  = ei + N_EDGES;
    const int*   batch = (const int*)d_in[2];
    const float* Wl0 = (const float*)d_in[3];
    const float* bl0 = (const float*)d_in[4];
    const float* Wr0 = (const float*)d_in[5];
    const float* Wl1 = (const float*)d_in[6];
    const float* bl1 = (const float*)d_in[7];
    const float* Wr1 = (const float*)d_in[8];
    const float* Wl2 = (const float*)d_in[9];
    const float* bl2 = (const float*)d_in[10];
    const float* Wr2 = (const float*)d_in[11];
    float* out = (float*)d_out;

    int*    cnt    = (int*)d_ws;                               // 65536 ints
    int*    bucket = cnt + 65536;                              // 3.2M ints
    ushort* xb     = (ushort*)(bucket + N_NODES * BUCKET_CAP); // 6.4M bf16
    ushort* aggb   = xb + (size_t)N_NODES * DIM;
    ushort* h1b    = aggb + (size_t)N_NODES * DIM;
    ushort* h2b    = h1b + (size_t)N_NODES * DIM;
    ushort* h3b    = h2b + (size_t)N_NODES * DIM;
    ushort* wb     = h3b + (size_t)N_NODES * DIM;              // 3 * 32768 bf16
    float*  pool   = (float*)(wb + 3 * DIM * KTOT);            // 8192 floats

    hipMemsetAsync(cnt, 0, N_NODES * sizeof(int), stream);
    hipMemsetAsync(pool, 0, N_GRAPHS * DIM * sizeof(float), stream);
    fill_kernel<<<(N_EDGES + 255) / 256, 256, 0, stream>>>(src, dst, cnt, bucket);
    castx_kernel<<<(N_NODES * DIM / 4 + 255) / 256, 256, 0, stream>>>(x, xb);
    castw_kernel<<<(3 * DIM * KTOT + 255) / 256, 256, 0, stream>>>(Wl0, Wr0, Wl1, Wr1, Wl2, Wr2, wb);

    const int ggrid = (N_NODES * 64 + 255) / 256;
    const int lgrid = (N_NODES + 63) / 64;

    gather_kernel<<<ggrid, 256, 0, stream>>>(xb, cnt, bucket, aggb);
    layer_mfma<<<lgrid, 512, 0, stream>>>(aggb, xb, wb,             bl0, h1b, 1);
    gather_kernel<<<ggrid, 256, 0, stream>>>(h1b, cnt, bucket, aggb);
    layer_mfma<<<lgrid, 512, 0, stream>>>(aggb, h1b, wb + 32768,    bl1, h2b, 1);
    gather_kernel<<<ggrid, 256, 0, stream>>>(h2b, cnt, bucket, aggb);
    layer_mfma<<<lgrid, 512, 0, stream>>>(aggb, h2b, wb + 65536,    bl2, h3b, 0);

    pool1_kernel<<<P_BLOCKS, DIM, 0, stream>>>(h3b, batch, pool);
    pool2_kernel<<<N_GRAPHS, DIM, 0, stream>>>(pool, batch, out);
}

// Round 6
// 348.556 us; speedup vs baseline: 13.6253x; 1.0456x over previous
//
#include <hip/hip_runtime.h>

#define N_NODES 50000
#define N_EDGES 800000
#define DIM 128
#define KTOT 256        // [agg | x] concatenated along k
#define N_GRAPHS 64
#define BUCKET_CAP 64
#define P_BLOCKS 512
#define LSTR 264        // LDS A-tile row stride in bf16 (+8 pad -> conflict-free b128)

typedef __attribute__((ext_vector_type(8))) short bf16x8;
typedef __attribute__((ext_vector_type(16))) float f32x16;

__device__ __forceinline__ float bf2f(unsigned int u16) {
    return __uint_as_float(u16 << 16);
}
__device__ __forceinline__ unsigned short f2bf(float f) {
    unsigned int v = __float_as_uint(f);
    unsigned int r = (v + 0x7fffu + ((v >> 16) & 1u)) >> 16;   // RNE
    return (unsigned short)r;
}

// ---------- setup: buckets + casts ----------
// ushort buckets: src < 50000 fits 16 bits; halves scatter write-amplification.
__global__ void fill_kernel(const int* __restrict__ src, const int* __restrict__ dst,
                            int* __restrict__ cnt, ushort* __restrict__ bucket) {
    int e = blockIdx.x * blockDim.x + threadIdx.x;
    if (e >= N_EDGES) return;
    int d = dst[e];
    int pos = atomicAdd(&cnt[d], 1);
    if (pos < BUCKET_CAP) bucket[d * BUCKET_CAP + pos] = (ushort)src[e];
}

// also zeros cnt (must run before fill_kernel)
__global__ void castx_kernel(const float* __restrict__ x, ushort* __restrict__ xb,
                             int* __restrict__ cnt) {
    int i = blockIdx.x * blockDim.x + threadIdx.x;   // float4 index
    if (i < N_NODES) cnt[i] = 0;
    if (i >= N_NODES * DIM / 4) return;
    float4 v = ((const float4*)x)[i];
    ushort4 o;
    o.x = f2bf(v.x); o.y = f2bf(v.y); o.z = f2bf(v.z); o.w = f2bf(v.w);
    ((ushort4*)xb)[i] = o;
}

// wb layout per layer: [128 j][256 k] with k<128 = Wl, k>=128 = Wr. Also zeros pool.
__global__ void castw_kernel(const float* __restrict__ Wl0, const float* __restrict__ Wr0,
                             const float* __restrict__ Wl1, const float* __restrict__ Wr1,
                             const float* __restrict__ Wl2, const float* __restrict__ Wr2,
                             ushort* __restrict__ wb, float* __restrict__ pool) {
    int id = blockIdx.x * blockDim.x + threadIdx.x;   // 3*128*256 = 98304
    if (id < N_GRAPHS * DIM) pool[id] = 0.f;
    if (id >= 3 * DIM * KTOT) return;
    int l = id >> 15;
    int r = id & 32767;
    int j = r >> 8, k = r & 255;
    const float* Wl = (l == 0) ? Wl0 : (l == 1) ? Wl1 : Wl2;
    const float* Wr = (l == 0) ? Wr0 : (l == 1) ? Wr1 : Wr2;
    float v = (k < DIM) ? Wl[j * DIM + k] : Wr[j * DIM + k - DIM];
    wb[id] = f2bf(v);
}

// ---------- pull aggregation (bf16 in/out, fp32 accum) ----------
// One wave per node. Lane owns 4 cols (8 B); half-wave 0 takes even edges,
// half-wave 1 odd edges -> one load instr fetches TWO rows; 4-deep unroll = 8
// rows in flight. Halves combined via __shfl_xor(.,32).
__global__ __launch_bounds__(256) void gather_kernel(
    const ushort* __restrict__ X, const int* __restrict__ cnt,
    const ushort* __restrict__ bucket, ushort* __restrict__ agg) {
    int n = (blockIdx.x * blockDim.x + threadIdx.x) >> 6;
    int lane = threadIdx.x & 63;
    if (n >= N_NODES) return;
    int c = cnt[n];
    int cl = c < BUCKET_CAP ? c : BUCKET_CAP;
    const ushort* b = bucket + (size_t)n * BUCKET_CAP;
    const int half = lane >> 5, lcol = lane & 31;
    float a0 = 0.f, a1 = 0.f, a2 = 0.f, a3 = 0.f;
    int e = half;
    for (; e + 6 < cl; e += 8) {
        int s0 = b[e], s1 = b[e + 2], s2 = b[e + 4], s3 = b[e + 6];
        uint2 u0 = *(const uint2*)(X + (size_t)s0 * DIM + lcol * 4);
        uint2 u1 = *(const uint2*)(X + (size_t)s1 * DIM + lcol * 4);
        uint2 u2 = *(const uint2*)(X + (size_t)s2 * DIM + lcol * 4);
        uint2 u3 = *(const uint2*)(X + (size_t)s3 * DIM + lcol * 4);
        a0 += bf2f(u0.x & 0xffff) + bf2f(u1.x & 0xffff) + bf2f(u2.x & 0xffff) + bf2f(u3.x & 0xffff);
        a1 += bf2f(u0.x >> 16)    + bf2f(u1.x >> 16)    + bf2f(u2.x >> 16)    + bf2f(u3.x >> 16);
        a2 += bf2f(u0.y & 0xffff) + bf2f(u1.y & 0xffff) + bf2f(u2.y & 0xffff) + bf2f(u3.y & 0xffff);
        a3 += bf2f(u0.y >> 16)    + bf2f(u1.y >> 16)    + bf2f(u2.y >> 16)    + bf2f(u3.y >> 16);
    }
    for (; e < cl; e += 2) {
        int s0 = b[e];
        uint2 u0 = *(const uint2*)(X + (size_t)s0 * DIM + lcol * 4);
        a0 += bf2f(u0.x & 0xffff);
        a1 += bf2f(u0.x >> 16);
        a2 += bf2f(u0.y & 0xffff);
        a3 += bf2f(u0.y >> 16);
    }
    a0 += __shfl_xor(a0, 32);
    a1 += __shfl_xor(a1, 32);
    a2 += __shfl_xor(a2, 32);
    a3 += __shfl_xor(a3, 32);
    if (half == 0) {
        float inv = 1.0f / (float)(c > 0 ? c : 1);
        uint2 o;
        o.x = ((unsigned int)f2bf(a1 * inv) << 16) | f2bf(a0 * inv);
        o.y = ((unsigned int)f2bf(a3 * inv) << 16) | f2bf(a2 * inv);
        *(uint2*)(agg + (size_t)n * DIM + lcol * 4) = o;
    }
}

// ---------- MFMA layer: out[50000x128] = [agg|h][50000x256] . W[128x256]^T ----------
__global__ __launch_bounds__(512, 4) void layer_mfma(
    const ushort* __restrict__ aggb, const ushort* __restrict__ hb,
    const ushort* __restrict__ wb, const float* __restrict__ bl,
    ushort* __restrict__ outb, int relu)
{
    __shared__ ushort sA[64 * LSTR];
    const int tid = threadIdx.x;
    const int lane = tid & 63, w = tid >> 6;
    const int mh = w & 1, jq = w >> 1;
    const int n0 = blockIdx.x * 64;

    // W fragments: lane l holds W[jq*32 + (l&31)][kt*16 + (l>>5)*8 .. +7]
    bf16x8 bw[16];
    {
        const ushort* wp = wb + (size_t)(jq * 32 + (lane & 31)) * KTOT + (lane >> 5) * 8;
        #pragma unroll
        for (int kt = 0; kt < 16; ++kt)
            bw[kt] = *(const bf16x8*)(wp + kt * 16);
    }

    // Stage A tile: 64 rows x 256 bf16 (k<128 from aggb, else hb)
    #pragma unroll
    for (int it = 0; it < 4; ++it) {
        int ci = tid + it * 512;
        int row = ci >> 5;
        int k8 = (ci & 31) * 8;
        int gn = n0 + row;
        bf16x8 v = (bf16x8){0,0,0,0,0,0,0,0};
        if (gn < N_NODES) {
            const ushort* p = (k8 < DIM) ? (aggb + (size_t)gn * DIM + k8)
                                         : (hb + (size_t)gn * DIM + (k8 - DIM));
            v = *(const bf16x8*)p;
        }
        *(bf16x8*)(&sA[row * LSTR + k8]) = v;
    }
    __syncthreads();

    f32x16 acc = {};
    const int arow = mh * 32 + (lane & 31);
    const int akoff = (lane >> 5) * 8;
    #pragma unroll
    for (int kt = 0; kt < 16; ++kt) {
        bf16x8 a = *(const bf16x8*)(&sA[arow * LSTR + kt * 16 + akoff]);
        acc = __builtin_amdgcn_mfma_f32_32x32x16_bf16(a, bw[kt], acc, 0, 0, 0);
    }

    // C/D map: col=lane&31, row=(reg&3)+8*(reg>>2)+4*(lane>>5)  [m74/m101]
    const int col = lane & 31;
    const int j = jq * 32 + col;
    const float bias = bl[j];
    #pragma unroll
    for (int r = 0; r < 16; ++r) {
        int row = (r & 3) + 8 * (r >> 2) + 4 * (lane >> 5);
        int gn = n0 + mh * 32 + row;
        if (gn < N_NODES) {
            float v = acc[r] + bias;
            if (relu) v = fmaxf(v, 0.f);
            outb[(size_t)gn * DIM + j] = f2bf(v);
        }
    }
}

// ---------- pool ----------
__global__ void pool1_kernel(const ushort* __restrict__ H, const int* __restrict__ batch,
                             float* __restrict__ pool) {
    const int per = (N_NODES + P_BLOCKS - 1) / P_BLOCKS;
    int n0 = blockIdx.x * per;
    int n1 = n0 + per; if (n1 > N_NODES) n1 = N_NODES;
    if (n0 >= n1) return;
    int j = threadIdx.x;
    float acc = 0.f;
    int g = batch[n0];
    for (int n = n0; n < n1; ++n) {
        int bg = batch[n];
        if (bg != g) {
            unsafeAtomicAdd(&pool[g * DIM + j], acc);
            acc = 0.f; g = bg;
        }
        acc += bf2f(H[(size_t)n * DIM + j]);
    }
    unsafeAtomicAdd(&pool[g * DIM + j], acc);
}

__global__ void pool2_kernel(const float* __restrict__ pool, const int* __restrict__ batch,
                             float* __restrict__ out) {
    int g = blockIdx.x;
    int j = threadIdx.x;
    int lo = 0, hi = N_NODES;
    while (lo < hi) { int m = (lo + hi) >> 1; if (batch[m] < g) lo = m + 1; else hi = m; }
    int start = lo;
    lo = start; hi = N_NODES;
    while (lo < hi) { int m = (lo + hi) >> 1; if (batch[m] < g + 1) lo = m + 1; else hi = m; }
    int cnt = lo - start;
    out[g * DIM + j] = pool[g * DIM + j] / (float)(cnt > 0 ? cnt : 1);
}

extern "C" void kernel_launch(void* const* d_in, const int* in_sizes, int n_in,
                              void* d_out, int out_size, void* d_ws, size_t ws_size,
                              hipStream_t stream) {
    const float* x    = (const float*)d_in[0];
    const int*   ei   = (const int*)d_in[1];
    const int*   src  = ei;
    const int*   dst  = ei + N_EDGES;
    const int*   batch = (const int*)d_in[2];
    const float* Wl0 = (const float*)d_in[3];
    const float* bl0 = (const float*)d_in[4];
    const float* Wr0 = (const float*)d_in[5];
    const float* Wl1 = (const float*)d_in[6];
    const float* bl1 = (const float*)d_in[7];
    const float* Wr1 = (const float*)d_in[8];
    const float* Wl2 = (const float*)d_in[9];
    const float* bl2 = (const float*)d_in[10];
    const float* Wr2 = (const float*)d_in[11];
    float* out = (float*)d_out;

    int*    cnt    = (int*)d_ws;                               // 65536 ints
    ushort* bucket = (ushort*)(cnt + 65536);                   // 3.2M ushorts
    ushort* xb     = bucket + (size_t)N_NODES * BUCKET_CAP;
    ushort* aggb   = xb + (size_t)N_NODES * DIM;
    ushort* h1b    = aggb + (size_t)N_NODES * DIM;
    ushort* h2b    = h1b + (size_t)N_NODES * DIM;
    ushort* h3b    = h2b + (size_t)N_NODES * DIM;
    ushort* wb     = h3b + (size_t)N_NODES * DIM;              // 3 * 32768 bf16
    float*  pool   = (float*)(wb + 3 * DIM * KTOT);            // 8192 floats

    castx_kernel<<<(N_NODES * DIM / 4 + 255) / 256, 256, 0, stream>>>(x, xb, cnt);
    castw_kernel<<<(3 * DIM * KTOT + 255) / 256, 256, 0, stream>>>(Wl0, Wr0, Wl1, Wr1, Wl2, Wr2, wb, pool);
    fill_kernel<<<(N_EDGES + 255) / 256, 256, 0, stream>>>(src, dst, cnt, bucket);

    const int ggrid = (N_NODES * 64 + 255) / 256;
    const int lgrid = (N_NODES + 63) / 64;

    gather_kernel<<<ggrid, 256, 0, stream>>>(xb, cnt, bucket, aggb);
    layer_mfma<<<lgrid, 512, 0, stream>>>(aggb, xb, wb,          bl0, h1b, 1);
    gather_kernel<<<ggrid, 256, 0, stream>>>(h1b, cnt, bucket, aggb);
    layer_mfma<<<lgrid, 512, 0, stream>>>(aggb, h1b, wb + 32768, bl1, h2b, 1);
    gather_kernel<<<ggrid, 256, 0, stream>>>(h2b, cnt, bucket, aggb);
    layer_mfma<<<lgrid, 512, 0, stream>>>(aggb, h2b, wb + 65536, bl2, h3b, 0);

    pool1_kernel<<<P_BLOCKS, DIM, 0, stream>>>(h3b, batch, pool);
    pool2_kernel<<<N_GRAPHS, DIM, 0, stream>>>(pool, batch, out);
}